// Round 8
// baseline (591.602 us; speedup 1.0000x reference)
//
#include <hip/hip_runtime.h>
#include <hip/hip_bf16.h>
#include <float.h>
#include <limits.h>

#define NTOK 8192   // B*S
#define H_   2048
#define P_   4096
#define D_   1024
#define I_   1024

#define MAXC  16          // max recheck candidates per token
#define DELTA 0.09375f    // candidate margin (approx-logit worst err ~0.007)
#define TAU   4.0e-4f     // near-tie margin for exact fallback
#define FLAGCAP 512       // capped so part[] overlays the dead logitsb region

typedef unsigned short ushort_t;
typedef __attribute__((ext_vector_type(8))) short short8;   // 8 bf16 = 4 VGPRs
typedef __attribute__((ext_vector_type(4))) float floatx4;  // MFMA accumulator

static __device__ inline ushort_t f2bf(float f) {
    __hip_bfloat16 h = __float2bfloat16(f);   // RNE
    return *reinterpret_cast<ushort_t*>(&h);
}
static __device__ inline short f2bfs(float f) {
    __hip_bfloat16 h = __float2bfloat16(f);
    return *reinterpret_cast<short*>(&h);
}
static __device__ inline float bf2f(ushort_t s) { return __uint_as_float((unsigned)s << 16); }

static __device__ inline void ins2(float& v0, int& i0, float& v1, int& i1, float v, int i) {
    if (v > v0 || (v == v0 && i < i0)) { v1 = v0; i1 = i0; v0 = v; i0 = i; }
    else if (v > v1 || (v == v1 && i < i1)) { v1 = v; i1 = i; }
}

// direct global->LDS DMA, 16 B per lane (dest = wave-uniform base + lane*16)
static __device__ __forceinline__ void gload16(const void* g, void* l) {
    __builtin_amdgcn_global_load_lds(
        (const __attribute__((address_space(1))) unsigned int*)g,
        (__attribute__((address_space(3))) unsigned int*)l,
        16, 0, 0);
}

// ---------------------------------------------------------------------------
// split f32 -> bf16 hi + bf16 lo (RNE both; v = hi + lo + O(2^-18 v))
// ---------------------------------------------------------------------------
__global__ __launch_bounds__(256) void split_x(
    const float* __restrict__ in, ushort_t* __restrict__ hi,
    ushort_t* __restrict__ lo, int n4)
{
    int idx = blockIdx.x * 256 + threadIdx.x;
    const int stride = gridDim.x * 256;
    for (; idx < n4; idx += stride) {
        float4 v = ((const float4*)in)[idx];
        ushort4 h, l;
        h.x = f2bf(v.x); l.x = f2bf(v.x - bf2f(h.x));
        h.y = f2bf(v.y); l.y = f2bf(v.y - bf2f(h.y));
        h.z = f2bf(v.z); l.z = f2bf(v.z - bf2f(h.z));
        h.w = f2bf(v.w); l.w = f2bf(v.w - bf2f(h.w));
        ((ushort4*)hi)[idx] = h;
        ((ushort4*)lo)[idx] = l;
    }
}

// ---------------------------------------------------------------------------
// fused weight prep (one launch): w2 -> w2t bf16 + w2tf f32 (transposed);
// wp -> wpt bf16; wm -> wmt bf16; w1 -> w1tHi/w1tLo bf16 split. All transposed.
// ---------------------------------------------------------------------------
__global__ __launch_bounds__(256) void prep_weights(
    const float* __restrict__ w2, float* __restrict__ w2tf, ushort_t* __restrict__ w2t,
    const float* __restrict__ wp, ushort_t* __restrict__ wpt,
    const float* __restrict__ wm, ushort_t* __restrict__ wmt,
    const float* __restrict__ w1, ushort_t* __restrict__ w1tHi, ushort_t* __restrict__ w1tLo)
{
    __shared__ float tile[32][33];
    const int tid = threadIdx.x;
    const int tx = tid & 31, ty = tid >> 5;   // 32 x 8
    int b = blockIdx.x;
    const float* in; int R, Cc, seg, bx, by;
    if (b < 4096)      { seg = 0; in = w2; R = I_; Cc = P_; bx = b & 127; by = b >> 7; }
    else if (b < 6144) { seg = 1; b -= 4096; in = wp; R = H_; Cc = D_; bx = b & 31; by = b >> 5; }
    else if (b < 8192) { seg = 2; b -= 6144; in = wm; R = H_; Cc = D_; bx = b & 31; by = b >> 5; }
    else               { seg = 3; b -= 8192; in = w1; R = H_; Cc = I_; bx = b & 31; by = b >> 5; }
    const int c0 = bx * 32, r0 = by * 32;
#pragma unroll
    for (int j = 0; j < 4; j++)
        tile[ty + j * 8][tx] = in[(size_t)(r0 + ty + j * 8) * Cc + c0 + tx];
    __syncthreads();
#pragma unroll
    for (int j = 0; j < 4; j++) {
        float v = tile[tx][ty + j * 8];
        const size_t o = (size_t)(c0 + ty + j * 8) * R + r0 + tx;
        if (seg == 0)      { w2t[o] = f2bf(v); w2tf[o] = v; }
        else if (seg == 1) { wpt[o] = f2bf(v); }
        else if (seg == 2) { wmt[o] = f2bf(v); }
        else { ushort_t h = f2bf(v); w1tHi[o] = h; w1tLo[o] = f2bf(v - bf2f(h)); }
    }
}

// ---------------------------------------------------------------------------
// pipeline staging helper: 16B slot p <-> (row=p>>2, chunk=(p^(p>>2))&3);
// inverse-swizzled SOURCE addr + linear LDS dest (both-sides rule).
// ---------------------------------------------------------------------------
static __device__ __forceinline__ void stage_slot(
    const ushort_t* __restrict__ base, int ld, int r0, int kt, int p,
    ushort_t* __restrict__ lds)
{
    const int row = p >> 2;
    const int chunk = (p ^ (p >> 2)) & 3;
    gload16(base + (size_t)(r0 + row) * ld + kt * 32 + chunk * 8, lds + p * 8);
}

// ---------------------------------------------------------------------------
// 256x128 deep-pipelined bf16 MFMA GEMM (T2/T3/T4/T5), plain bf16 operands.
// 512 thr = 8 waves (4M x 2N); per-wave C = 64x64 (4x4 frags of 16x16).
// LDS = 3 x (A 16KB + B 8KB) = 72 KB -> 2 blocks/CU. Steady gate vmcnt(3).
// ---------------------------------------------------------------------------
template<int EPI>
__global__ __launch_bounds__(512, 2) void gemm_pipe(
    const ushort_t* __restrict__ A, int lda,
    const ushort_t* __restrict__ Bt, int ldb,
    const float* __restrict__ bias,
    float* __restrict__ Cf, ushort_t* __restrict__ Cb, int ldc, int K)
{
    __shared__ ushort_t sA[3][256 * 32];   // 3 x 16 KB
    __shared__ ushort_t sB[3][128 * 32];   // 3 x  8 KB  -> 72 KB total

    const int tid  = threadIdx.x;
    const int wave = tid >> 6, lane = tid & 63;
    const int lr = lane & 15, lq = lane >> 4;
    const int wrow = wave >> 1, wcol = wave & 1;   // 4M x 2N

    const int nwg = gridDim.x * gridDim.y;
    int bid = blockIdx.y * gridDim.x + blockIdx.x;
    bid = (bid & 7) * (nwg >> 3) + (bid >> 3);
    const int bx = bid % gridDim.x, by = bid / gridDim.x;
    const int m0 = by * 256, n0 = bx * 128;
    const int NT = K >> 5;

    floatx4 acc[4][4] = {};

    stage_slot(A,  lda, m0, 0, tid,       &sA[0][0]);
    stage_slot(A,  lda, m0, 0, tid + 512, &sA[0][0]);
    stage_slot(Bt, ldb, n0, 0, tid,       &sB[0][0]);
    stage_slot(A,  lda, m0, 1, tid,       &sA[1][0]);
    stage_slot(A,  lda, m0, 1, tid + 512, &sA[1][0]);
    stage_slot(Bt, ldb, n0, 1, tid,       &sB[1][0]);

    for (int kt = 0; kt < NT; kt++) {
        const int cb = kt % 3;
        const int sbuf = (kt + 2) % 3;
        const bool st = (kt + 2) < NT;
        const ushort_t* __restrict__ sAc = &sA[cb][0];
        const ushort_t* __restrict__ sBc = &sB[cb][0];
        short8 bF[4];

#pragma unroll
        for (int p = 0; p < 2; p++) {
            if (p == 0) {
                if (kt + 1 < NT) asm volatile("s_waitcnt vmcnt(3)" ::: "memory");
                else             asm volatile("s_waitcnt vmcnt(0)" ::: "memory");
            }
            __builtin_amdgcn_s_barrier();
            short8 aF[2];
#pragma unroll
            for (int t = 0; t < 2; t++) {
                const int row = wrow * 64 + (2 * p + t) * 16 + lr;
                const int ph = row * 4 + (lq ^ (row & 3));
                aF[t] = *(const short8*)&sAc[ph * 8];
            }
            if (p == 0) {
#pragma unroll
                for (int f = 0; f < 4; f++) {
                    const int row = wcol * 64 + f * 16 + lr;
                    const int ph = row * 4 + (lq ^ (row & 3));
                    bF[f] = *(const short8*)&sBc[ph * 8];
                }
            }
            if (st) {
                if (p == 0) {
                    stage_slot(A,  lda, m0, kt + 2, tid, &sA[sbuf][0]);
                    stage_slot(Bt, ldb, n0, kt + 2, tid, &sB[sbuf][0]);
                } else {
                    stage_slot(A,  lda, m0, kt + 2, tid + 512, &sA[sbuf][0]);
                }
            }
            __builtin_amdgcn_s_setprio(1);
#pragma unroll
            for (int t = 0; t < 2; t++)
#pragma unroll
                for (int j = 0; j < 4; j++)
                    acc[2 * p + t][j] = __builtin_amdgcn_mfma_f32_16x16x32_bf16(
                        aF[t], bF[j], acc[2 * p + t][j], 0, 0, 0);
            __builtin_amdgcn_s_setprio(0);
        }
    }

#pragma unroll
    for (int j = 0; j < 4; j++) {
        const int col = n0 + wcol * 64 + j * 16 + lr;
        const float bv = bias[col];
#pragma unroll
        for (int i = 0; i < 4; i++) {
            const int rowb = m0 + wrow * 64 + i * 16 + lq * 4;
#pragma unroll
            for (int r = 0; r < 4; r++) {
                float v = acc[i][j][r] + bv;
                if (EPI == 1) Cb[(size_t)(rowb + r) * ldc + col] = f2bf(v);
                else          Cf[(size_t)(rowb + r) * ldc + col] = v;
            }
        }
    }
}

// ---------------------------------------------------------------------------
// 256x128 deep-pipelined SPLIT bf16 MFMA GEMM (near-fp32):
//   C = relu( (AH+AL) @ (BH+BL)^T + bias ), dropping lo*lo. 3 MFMAs/pair.
// Same pipeline skeleton as gemm_pipe; hi/lo doubles staging -> 6 loads/tile,
// steady gate vmcnt(6). LDS = 3 x (16+16+8+8) = 144 KB -> 1 block/CU.
// MFMA order (HH, HL, LH per (i,j), same k order) == old gemm_lds_split ->
// bitwise-identical inter; TAU fallback margins unchanged.
// Dual store: f32 Cf + bf16 Cb.
// ---------------------------------------------------------------------------
__global__ __launch_bounds__(512, 2) void gemm_pipe_split(
    const ushort_t* __restrict__ AH, const ushort_t* __restrict__ AL, int lda,
    const ushort_t* __restrict__ BtH, const ushort_t* __restrict__ BtL, int ldb,
    const float* __restrict__ bias,
    float* __restrict__ Cf, ushort_t* __restrict__ Cb, int ldc, int K)
{
    __shared__ ushort_t sAh[3][256 * 32];   // 48 KB
    __shared__ ushort_t sAl[3][256 * 32];   // 48 KB
    __shared__ ushort_t sBh[3][128 * 32];   // 24 KB
    __shared__ ushort_t sBl[3][128 * 32];   // 24 KB -> 144 KB total

    const int tid  = threadIdx.x;
    const int wave = tid >> 6, lane = tid & 63;
    const int lr = lane & 15, lq = lane >> 4;
    const int wrow = wave >> 1, wcol = wave & 1;   // 4M x 2N

    const int nwg = gridDim.x * gridDim.y;
    int bid = blockIdx.y * gridDim.x + blockIdx.x;
    bid = (bid & 7) * (nwg >> 3) + (bid >> 3);
    const int bx = bid % gridDim.x, by = bid / gridDim.x;
    const int m0 = by * 256, n0 = bx * 128;
    const int NT = K >> 5;

    floatx4 acc[4][4] = {};

    // prologue: tiles 0 and 1 (6 loads/thread each, tile-ordered)
#pragma unroll
    for (int t = 0; t < 2; t++) {
        stage_slot(AH,  lda, m0, t, tid,       &sAh[t][0]);
        stage_slot(AH,  lda, m0, t, tid + 512, &sAh[t][0]);
        stage_slot(AL,  lda, m0, t, tid,       &sAl[t][0]);
        stage_slot(AL,  lda, m0, t, tid + 512, &sAl[t][0]);
        stage_slot(BtH, ldb, n0, t, tid,       &sBh[t][0]);
        stage_slot(BtL, ldb, n0, t, tid,       &sBl[t][0]);
    }

    for (int kt = 0; kt < NT; kt++) {
        const int cb = kt % 3;
        const int sbuf = (kt + 2) % 3;
        const bool st = (kt + 2) < NT;
        const ushort_t* __restrict__ sAhc = &sAh[cb][0];
        const ushort_t* __restrict__ sAlc = &sAl[cb][0];
        const ushort_t* __restrict__ sBhc = &sBh[cb][0];
        const ushort_t* __restrict__ sBlc = &sBl[cb][0];
        short8 bH[4], bL[4];

#pragma unroll
        for (int p = 0; p < 2; p++) {
            if (p == 0) {
                // gate: tile kt complete (tile kt+1's 6 loads stay in flight)
                if (kt + 1 < NT) asm volatile("s_waitcnt vmcnt(6)" ::: "memory");
                else             asm volatile("s_waitcnt vmcnt(0)" ::: "memory");
            }
            __builtin_amdgcn_s_barrier();
            short8 aH[2], aL[2];
#pragma unroll
            for (int t = 0; t < 2; t++) {
                const int row = wrow * 64 + (2 * p + t) * 16 + lr;
                const int ph = (row * 4 + (lq ^ (row & 3))) * 8;
                aH[t] = *(const short8*)&sAhc[ph];
                aL[t] = *(const short8*)&sAlc[ph];
            }
            if (p == 0) {
#pragma unroll
                for (int f = 0; f < 4; f++) {
                    const int row = wcol * 64 + f * 16 + lr;
                    const int ph = (row * 4 + (lq ^ (row & 3))) * 8;
                    bH[f] = *(const short8*)&sBhc[ph];
                    bL[f] = *(const short8*)&sBlc[ph];
                }
            }
            // stage tile kt+2: phase 0 -> AH u0, AL u0, BH; phase 1 -> AH u1, AL u1, BL
            if (st) {
                if (p == 0) {
                    stage_slot(AH,  lda, m0, kt + 2, tid, &sAh[sbuf][0]);
                    stage_slot(AL,  lda, m0, kt + 2, tid, &sAl[sbuf][0]);
                    stage_slot(BtH, ldb, n0, kt + 2, tid, &sBh[sbuf][0]);
                } else {
                    stage_slot(AH,  lda, m0, kt + 2, tid + 512, &sAh[sbuf][0]);
                    stage_slot(AL,  lda, m0, kt + 2, tid + 512, &sAl[sbuf][0]);
                    stage_slot(BtL, ldb, n0, kt + 2, tid, &sBl[sbuf][0]);
                }
            }
            __builtin_amdgcn_s_setprio(1);
#pragma unroll
            for (int t = 0; t < 2; t++)
#pragma unroll
                for (int j = 0; j < 4; j++) {
                    acc[2 * p + t][j] = __builtin_amdgcn_mfma_f32_16x16x32_bf16(
                        aH[t], bH[j], acc[2 * p + t][j], 0, 0, 0);
                    acc[2 * p + t][j] = __builtin_amdgcn_mfma_f32_16x16x32_bf16(
                        aH[t], bL[j], acc[2 * p + t][j], 0, 0, 0);
                    acc[2 * p + t][j] = __builtin_amdgcn_mfma_f32_16x16x32_bf16(
                        aL[t], bH[j], acc[2 * p + t][j], 0, 0, 0);
                }
            __builtin_amdgcn_s_setprio(0);
        }
    }

#pragma unroll
    for (int j = 0; j < 4; j++) {
        const int col = n0 + wcol * 64 + j * 16 + lr;
        const float bv = bias[col];
#pragma unroll
        for (int i = 0; i < 4; i++) {
            const int rowb = m0 + wrow * 64 + i * 16 + lq * 4;
#pragma unroll
            for (int r = 0; r < 4; r++) {
                float v = fmaxf(acc[i][j][r] + bv, 0.f);
                Cf[(size_t)(rowb + r) * ldc + col] = v;
                Cb[(size_t)(rowb + r) * ldc + col] = f2bf(v);
            }
        }
    }
}

// ---------------------------------------------------------------------------
// LDS-staged bf16 MFMA GEMM (m97 structure): 128x128 tile, BK=32, 4 waves.
// ASRC: 0 = A f32 (slot-based reg-stage + convert). Used for G4 (A = x f32).
// ---------------------------------------------------------------------------
template<int ASRC, int EPI>
__global__ __launch_bounds__(256) void gemm_lds(
    const void* __restrict__ Av, int lda,
    const ushort_t* __restrict__ Bt, int ldb,
    const float* __restrict__ bias,
    float* __restrict__ Cf, ushort_t* __restrict__ Cb, int ldc, int K)
{
    __shared__ ushort_t sA[128 * 32];   // 8 KB, row stride 32 elems (64 B)
    __shared__ ushort_t sB[128 * 32];   // 8 KB

    const int tid  = threadIdx.x;
    const int wave = tid >> 6, lane = tid & 63;
    const int lr = lane & 15, lq = lane >> 4;

    const int nwg = gridDim.x * gridDim.y;
    int bid = blockIdx.y * gridDim.x + blockIdx.x;
    bid = (bid & 7) * (nwg >> 3) + (bid >> 3);
    const int bx = bid % gridDim.x, by = bid / gridDim.x;
    const int m0 = by * 128, n0 = bx * 128;
    const int m0w = m0 + (wave >> 1) * 64, n0w = n0 + (wave & 1) * 64;

    const int n1 = tid, n2 = tid + 256;      // gload slot ids (16 B each)

    floatx4 acc[4][4] = {};

    for (int k0 = 0; k0 < K; k0 += 32) {
        __syncthreads();
        gload16(Bt + (size_t)(n0 + (n1 >> 2)) * ldb + k0 + (n1 & 3) * 8, &sB[n1 * 8]);
        gload16(Bt + (size_t)(n0 + (n2 >> 2)) * ldb + k0 + (n2 & 3) * 8, &sB[n2 * 8]);
        if (ASRC == 1) {
            const ushort_t* Ab = (const ushort_t*)Av;
            gload16(Ab + (size_t)(m0 + (n1 >> 2)) * lda + k0 + (n1 & 3) * 8, &sA[n1 * 8]);
            gload16(Ab + (size_t)(m0 + (n2 >> 2)) * lda + k0 + (n2 & 3) * 8, &sA[n2 * 8]);
        } else {
#pragma unroll
            for (int ss = 0; ss < 2; ss++) {
                const int s = tid + ss * 256;
                const float* ap = (const float*)Av + (size_t)(m0 + (s >> 2)) * lda + k0 + (s & 3) * 8;
                float4 v0 = *(const float4*)ap;
                float4 v1 = *(const float4*)(ap + 4);
                short8 h;
                h[0] = f2bfs(v0.x); h[1] = f2bfs(v0.y); h[2] = f2bfs(v0.z); h[3] = f2bfs(v0.w);
                h[4] = f2bfs(v1.x); h[5] = f2bfs(v1.y); h[6] = f2bfs(v1.z); h[7] = f2bfs(v1.w);
                *(short8*)&sA[s * 8] = h;
            }
        }
        __syncthreads();

        short8 aF[4], bF[4];
#pragma unroll
        for (int f = 0; f < 4; f++) {
            const int ra = ((wave >> 1) * 64 + f * 16 + lr) * 32 + lq * 8;
            aF[f] = *(const short8*)&sA[ra];
            const int rb = ((wave & 1) * 64 + f * 16 + lr) * 32 + lq * 8;
            bF[f] = *(const short8*)&sB[rb];
        }
#pragma unroll
        for (int i = 0; i < 4; i++)
#pragma unroll
            for (int j = 0; j < 4; j++)
                acc[i][j] = __builtin_amdgcn_mfma_f32_16x16x32_bf16(aF[i], bF[j], acc[i][j], 0, 0, 0);
    }

#pragma unroll
    for (int j = 0; j < 4; j++) {
        const int col = n0w + j * 16 + lr;
        const float bv = bias[col];
#pragma unroll
        for (int i = 0; i < 4; i++) {
            const int rowb = m0w + i * 16 + lq * 4;
#pragma unroll
            for (int r = 0; r < 4; r++) {
                float v = acc[i][j][r] + bv;
                if (EPI == 1) Cb[(size_t)(rowb + r) * ldc + col] = f2bf(v);
                else          Cf[(size_t)(rowb + r) * ldc + col] = v;
            }
        }
    }
}

// ---------------------------------------------------------------------------
// per-token: approx top-2 over bf16 logits; emit all indices within DELTA of
// the 2nd max (always includes the approx top-2 themselves), cap MAXC
// ---------------------------------------------------------------------------
__global__ __launch_bounds__(256) void cand_scan(
    const ushort_t* __restrict__ logitsb,
    int* __restrict__ cidx, int* __restrict__ ccnt)
{
    __shared__ float sv0[4], sv1[4];
    __shared__ int   scnt;
    const int tok = blockIdx.x;
    const int tid = threadIdx.x;
    const ushort_t* row = logitsb + (size_t)tok * P_;

    float my[16];
    {
        const uint4* rp = (const uint4*)(row + tid * 16);
        uint4 u0 = rp[0], u1 = rp[1];
        unsigned w[8] = {u0.x, u0.y, u0.z, u0.w, u1.x, u1.y, u1.z, u1.w};
#pragma unroll
        for (int j = 0; j < 8; j++) {
            my[2 * j]     = __uint_as_float(w[j] << 16);
            my[2 * j + 1] = __uint_as_float(w[j] & 0xFFFF0000u);
        }
    }
    float v0 = -FLT_MAX, v1 = -FLT_MAX;
#pragma unroll
    for (int j = 0; j < 16; j++) {
        float v = my[j];
        if (v > v0) { v1 = v0; v0 = v; } else if (v > v1) v1 = v;
    }
#pragma unroll
    for (int off = 1; off < 64; off <<= 1) {
        float u0 = __shfl_xor(v0, off), u1 = __shfl_xor(v1, off);
        float n0 = fmaxf(v0, u0);
        float n1 = fmaxf(fminf(v0, u0), fmaxf(v1, u1));
        v0 = n0; v1 = n1;
    }
    const int wv = tid >> 6;
    if ((tid & 63) == 0) { sv0[wv] = v0; sv1[wv] = v1; }
    if (tid == 0) scnt = 0;
    __syncthreads();
    float g0 = -FLT_MAX, g1 = -FLT_MAX;
#pragma unroll
    for (int w = 0; w < 4; w++) {
        float u0 = sv0[w], u1 = sv1[w];
        float n0 = fmaxf(g0, u0);
        float n1 = fmaxf(fminf(g0, u0), fmaxf(g1, u1));
        g0 = n0; g1 = n1;
    }
    const float thresh = g1 - DELTA;
#pragma unroll
    for (int j = 0; j < 16; j++) {
        if (my[j] >= thresh) {
            int pos = atomicAdd(&scnt, 1);
            if (pos < MAXC) cidx[tok * MAXC + pos] = tid * 16 + j;
        }
    }
    __syncthreads();
    if (tid == 0) ccnt[tok] = min(scnt, MAXC);
}

// ---------------------------------------------------------------------------
// exact f64 recheck of candidate logits -> exact top-2 + softmax weights.
// If the (rank2 - rank3) gap is < TAU, flag the token for the exact fallback.
// ---------------------------------------------------------------------------
__global__ __launch_bounds__(256) void recheck(
    const float* __restrict__ interf, const float* __restrict__ w2tf,
    const float* __restrict__ b2, const int* __restrict__ cidx,
    const int* __restrict__ ccnt, const float* __restrict__ temp_p,
    int2* __restrict__ tki, float2* __restrict__ tkw,
    int* __restrict__ flagcnt, int* __restrict__ flaglist)
{
    __shared__ double ex[MAXC];
    __shared__ int    sidx[MAXC];
    const int tok  = blockIdx.x;
    const int tid  = threadIdx.x;
    const int wave = tid >> 6, lane = tid & 63;
    int cnt = min(max(ccnt[tok], 0), MAXC);

    const float* ir = interf + (size_t)tok * I_;
    for (int c = wave; c < cnt; c += 4) {
        int p = min(max(cidx[tok * MAXC + c], 0), P_ - 1);
        const float* wr = w2tf + (size_t)p * I_;
        double s = 0.0;
        for (int k = lane; k < I_; k += 64)
            s += (double)ir[k] * (double)wr[k];
#pragma unroll
        for (int off = 32; off; off >>= 1) s += __shfl_down(s, off);
        if (lane == 0) { ex[c] = s + (double)b2[p]; sidx[c] = p; }
    }
    __syncthreads();
    if (tid == 0) {
        float v0 = -FLT_MAX, v1 = -FLT_MAX; int i0 = INT_MAX, i1 = INT_MAX;
        for (int c = 0; c < cnt; c++) ins2(v0, i0, v1, i1, (float)ex[c], sidx[c]);
        if (i0 == INT_MAX) { i0 = 0; v0 = 0.f; }
        if (i1 == INT_MAX) { i1 = i0; v1 = v0; }
        if (cnt >= 3) {
            float v2 = -FLT_MAX;
            for (int c = 0; c < cnt; c++) {
                if (sidx[c] == i0 || sidx[c] == i1) continue;
                float v = (float)ex[c];
                if (v > v2) v2 = v;
            }
            if (v1 - v2 < TAU) {
                int pos = atomicAdd(flagcnt, 1);
                if (pos < FLAGCAP) flaglist[pos] = tok;
            }
        }
        float tc = fminf(fmaxf(temp_p[0], 0.1f), 5.0f);
        float s0 = fminf(fmaxf(v0 / tc, -10.f), 10.f);
        float s1 = fminf(fmaxf(v1 / tc, -10.f), 10.f);
        float m  = fmaxf(s0, s1);
        float e0 = expf(s0 - m), e1 = expf(s1 - m);
        float inv = 1.0f / (e0 + e1);
        tki[tok] = make_int2(i0, i1);
        tkw[tok] = make_float2(e0 * inv, e1 * inv);
    }
}

// ---------------------------------------------------------------------------
// fallback phase A: 16 blocks per flagged token; block (fi, slice) computes
// f64 partial inter over h in [slice*128, slice*128+128) for all 1024 i.
// ---------------------------------------------------------------------------
__global__ __launch_bounds__(256) void fallback_gemv(
    const float* __restrict__ x, const float* __restrict__ w1,
    const int* __restrict__ flagcnt, const int* __restrict__ flaglist,
    double* __restrict__ part)
{
    __shared__ float sx[128];
    const int tid = threadIdx.x;
    const int nf = min(flagcnt[0], FLAGCAP);
    const int nitems = nf * 16;

    for (int idx = blockIdx.x; idx < nitems; idx += gridDim.x) {
        const int fi = idx >> 4, slice = idx & 15;
        const int tok = flaglist[fi];
        const int h0 = slice * 128;
        __syncthreads();   // protect sx reuse across idx iterations
        if (tid < 128) sx[tid] = x[(size_t)tok * H_ + h0 + tid];
        __syncthreads();

        const int col = tid * 4;
        double a0 = 0.0, a1 = 0.0, a2 = 0.0, a3 = 0.0;
        for (int h = 0; h < 128; h += 8) {
            float4 wv[8];
#pragma unroll
            for (int u = 0; u < 8; u++)
                wv[u] = *(const float4*)(w1 + (size_t)(h0 + h + u) * I_ + col);
#pragma unroll
            for (int u = 0; u < 8; u++) {
                const double xv = (double)sx[h + u];
                a0 += xv * (double)wv[u].x;
                a1 += xv * (double)wv[u].y;
                a2 += xv * (double)wv[u].z;
                a3 += xv * (double)wv[u].w;
            }
        }
        double* pp = part + ((size_t)fi * 16 + slice) * I_ + col;
        pp[0] = a0; pp[1] = a1; pp[2] = a2; pp[3] = a3;
    }
}

// ---------------------------------------------------------------------------
// fallback phase B: per flagged token, reduce 16 partials + bias + relu ->
// exact candidate logits (f64) -> top-2 + softmax weights.
// ---------------------------------------------------------------------------
__global__ __launch_bounds__(256) void fallback_reduce(
    const double* __restrict__ part, const float* __restrict__ b1,
    const float* __restrict__ w2tf, const float* __restrict__ b2,
    const int* __restrict__ cidx, const int* __restrict__ ccnt,
    const int* __restrict__ flagcnt, const int* __restrict__ flaglist,
    const float* __restrict__ temp_p,
    int2* __restrict__ tki, float2* __restrict__ tkw)
{
    __shared__ double sInter[I_];   // 8 KB
    __shared__ double ex[MAXC];
    __shared__ int    sidx[MAXC];
    const int tid  = threadIdx.x;
    const int wave = tid >> 6, lane = tid & 63;
    const int nf = min(flagcnt[0], FLAGCAP);

    for (int fi = blockIdx.x; fi < nf; fi += gridDim.x) {
        const int tok = flaglist[fi];
        __syncthreads();   // protect LDS reuse across fi iterations
#pragma unroll
        for (int q = 0; q < 4; q++) {
            const int i = q * 256 + tid;
            double v = (double)b1[i];
            const double* pp = part + (size_t)fi * 16 * I_ + i;
#pragma unroll
            for (int s = 0; s < 16; s++) v += pp[(size_t)s * I_];
            sInter[i] = v > 0.0 ? v : 0.0;
        }
        __syncthreads();

        const int cnt = min(max(ccnt[tok], 0), MAXC);
        for (int c = wave; c < cnt; c += 4) {
            int p = min(max(cidx[tok * MAXC + c], 0), P_ - 1);
            const float* wr = w2tf + (size_t)p * I_;
            double s = 0.0;
            for (int k = lane; k < I_; k += 64)
                s += sInter[k] * (double)wr[k];
#pragma unroll
            for (int off = 32; off; off >>= 1) s += __shfl_down(s, off);
            if (lane == 0) { ex[c] = s + (double)b2[p]; sidx[c] = p; }
        }
        __syncthreads();
        if (tid == 0) {
            float v0 = -FLT_MAX, v1 = -FLT_MAX; int i0 = INT_MAX, i1 = INT_MAX;
            for (int c = 0; c < cnt; c++) ins2(v0, i0, v1, i1, (float)ex[c], sidx[c]);
            if (i0 == INT_MAX) { i0 = 0; v0 = 0.f; }
            if (i1 == INT_MAX) { i1 = i0; v1 = v0; }
            float tc = fminf(fmaxf(temp_p[0], 0.1f), 5.0f);
            float s0 = fminf(fmaxf(v0 / tc, -10.f), 10.f);
            float s1 = fminf(fmaxf(v1 / tc, -10.f), 10.f);
            float m  = fmaxf(s0, s1);
            float e0 = expf(s0 - m), e1 = expf(s1 - m);
            float inv = 1.0f / (e0 + e1);
            tki[tok] = make_int2(i0, i1);
            tkw[tok] = make_float2(e0 * inv, e1 * inv);
        }
    }
}

// ---------------------------------------------------------------------------
static __device__ inline float blockReduceSum256(float v, float* red) {
#pragma unroll
    for (int off = 32; off; off >>= 1) v += __shfl_down(v, off);
    const int wv = threadIdx.x >> 6;
    if ((threadIdx.x & 63) == 0) red[wv] = v;
    __syncthreads();
    float tot = red[0] + red[1] + red[2] + red[3];
    __syncthreads();
    return tot;
}

// ---------------------------------------------------------------------------
// combined(bf16)[tok] = [ LN(proj)*gamma+beta , w0*pool[i0]+w1*pool[i1] ] + usage
// ---------------------------------------------------------------------------
__global__ __launch_bounds__(256) void build_combined(
    const float* __restrict__ proj, ushort_t* __restrict__ comb,
    const float* __restrict__ pool,
    const float* __restrict__ gamma, const float* __restrict__ beta,
    const int2* __restrict__ tki, const float2* __restrict__ tkw,
    float* __restrict__ usage)
{
    __shared__ float red[4];
    const int tok = blockIdx.x;
    const int tid = threadIdx.x;
    const int c = tid * 4;

    float4 v = *(const float4*)&proj[(size_t)tok * D_ + c];
    float s = v.x + v.y + v.z + v.w;
    float tot = blockReduceSum256(s, red);
    float mu = tot * (1.0f / D_);
    float d0 = v.x - mu, d1 = v.y - mu, d2 = v.z - mu, d3 = v.w - mu;
    float sq = d0 * d0 + d1 * d1 + d2 * d2 + d3 * d3;
    float var = blockReduceSum256(sq, red) * (1.0f / D_);
    float rs = 1.0f / sqrtf(var + 1e-5f);

    float4 g  = *(const float4*)&gamma[c];
    float4 be = *(const float4*)&beta[c];
    ushort4 o;
    o.x = f2bf(d0 * rs * g.x + be.x);
    o.y = f2bf(d1 * rs * g.y + be.y);
    o.z = f2bf(d2 * rs * g.z + be.z);
    o.w = f2bf(d3 * rs * g.w + be.w);
    *(ushort4*)&comb[(size_t)tok * (2 * D_) + c] = o;

    int2   ii = tki[tok];
    int ia = min(max(ii.x, 0), P_ - 1);
    int ib = min(max(ii.y, 0), P_ - 1);
    float2 ww = tkw[tok];
    float4 p0 = *(const float4*)&pool[(size_t)ia * D_ + c];
    float4 p1 = *(const float4*)&pool[(size_t)ib * D_ + c];
    ushort4 wm;
    wm.x = f2bf(ww.x * p0.x + ww.y * p1.x);
    wm.y = f2bf(ww.x * p0.y + ww.y * p1.y);
    wm.z = f2bf(ww.x * p0.z + ww.y * p1.z);
    wm.w = f2bf(ww.x * p0.w + ww.y * p1.w);
    *(ushort4*)&comb[(size_t)tok * (2 * D_) + D_ + c] = wm;

    if (tid == 0) {
        atomicAdd(&usage[ia], ww.x);
        atomicAdd(&usage[ib], ww.y);
    }
}

// ---------------------------------------------------------------------------
__global__ __launch_bounds__(256) void diversity_kernel(
    const float* __restrict__ usage, float* __restrict__ out)
{
    __shared__ float red[4];
    const int tid = threadIdx.x;
    float s = 0.f;
    for (int j = tid; j < P_; j += 256) s += usage[j];
    float tot = blockReduceSum256(s, red) + 1e-8f;
    float q = 0.f;
    const float uni = 1.0f / P_;
    for (int j = tid; j < P_; j += 256) {
        float f = usage[j] / tot - uni;
        q += f * f;
    }
    float ssq = blockReduceSum256(q, red);
    if (tid == 0) out[(size_t)NTOK * D_] = ssq * (1.0f / P_) * 0.01f;
}

// ---------------------------------------------------------------------------
extern "C" void kernel_launch(void* const* d_in, const int* in_sizes, int n_in,
                              void* d_out, int out_size, void* d_ws, size_t ws_size,
                              hipStream_t stream) {
    const float* x     = (const float*)d_in[0];
    const float* pool  = (const float*)d_in[1];
    const float* w1    = (const float*)d_in[3];
    const float* b1    = (const float*)d_in[4];
    const float* w2    = (const float*)d_in[5];
    const float* b2    = (const float*)d_in[6];
    const float* temp  = (const float*)d_in[7];
    const float* wp    = (const float*)d_in[8];
    const float* bp    = (const float*)d_in[9];
    const float* gamma = (const float*)d_in[10];
    const float* beta  = (const float*)d_in[11];
    const float* wm    = (const float*)d_in[12];
    const float* bm    = (const float*)d_in[13];
    float* out = (float*)d_out;

    // workspace map (float offsets), peak ~153 MB:
    //  [0,8M)     interf f32 [8192][1024]
    //  [8M,12M)   interb bf16 [8192][1024]
    //  [12M,28M)  phase 0: xHi bf16 @12M, xLo bf16 @20M (split_x -> G1)
    //             phase 1: logitsb bf16 [8192][4096] (G2 -> cand_scan)
    //             phase 2: part f64 [512][16][1024] (fallback, 64 MB)
    //             phase 3: proj f32 @12M, combined bf16 @20M
    //  [28M,32M)  w2tf f32; [32M,34M) w2t; [34M,35M) wpt; [35M,36M) wmt
    //  [36M,37M)  w1tHi; [37M,38M) w1tLo; [38M,...) small buffers
    float* ws = (float*)d_ws;
    const size_t MF = (size_t)1024 * 1024;
    float*    interf  = ws;
    ushort_t* interb  = (ushort_t*)(ws + 8 * MF);
    ushort_t* xHi     = (ushort_t*)(ws + 12 * MF);
    ushort_t* xLo     = (ushort_t*)(ws + 20 * MF);
    ushort_t* logitsb = (ushort_t*)(ws + 12 * MF);
    double*   part    = (double*)(ws + 12 * MF);
    float*    projb   = ws + 12 * MF;
    ushort_t* comb    = (ushort_t*)(ws + 20 * MF);
    float*    w2tf    = ws + 28 * MF;
    ushort_t* w2t     = (ushort_t*)(ws + 32 * MF);
    ushort_t* wpt     = (ushort_t*)(ws + 34 * MF);
    ushort_t* wmt     = (ushort_t*)(ws + 35 * MF);
    ushort_t* w1tHi   = (ushort_t*)(ws + 36 * MF);
    ushort_t* w1tLo   = (ushort_t*)(ws + 37 * MF);
    int*      cidx    = (int*)(ws + 38 * MF);
    int*      ccnt    = cidx + NTOK * MAXC;
    int2*     tki     = (int2*)(ccnt + NTOK);
    float2*   tkw     = (float2*)(tki + NTOK);
    float*    usage   = (float*)(tkw + NTOK);
    int*      flagcnt = (int*)(usage + P_);
    int*      flaglist= flagcnt + 1;

    hipMemsetAsync(usage, 0, (P_ + 1) * sizeof(float), stream);  // usage + flagcnt

    dim3 blk(256);
    // fused weight prep
    prep_weights<<<10240, blk, 0, stream>>>(w2, w2tf, w2t, wp, wpt, wm, wmt,
                                            w1, w1tHi, w1tLo);

    // x -> bf16 hi/lo split (region reused by logitsb after G2)
    split_x<<<2048, blk, 0, stream>>>(x, xHi, xLo, NTOK * H_ / 4);

    // G1 (256x128 pipelined split-bf16 MFMA, near-fp32): inter = relu(x@w1+b1)
    gemm_pipe_split<<<dim3(I_ / 128, NTOK / 256), dim3(512), 0, stream>>>(
        xHi, xLo, H_, w1tHi, w1tLo, H_, b1, interf, interb, I_, H_);

    // G2 (256x128 pipelined bf16 MFMA, 1024 blocks): approx logits (bf16 store)
    gemm_pipe<1><<<dim3(P_ / 128, NTOK / 256), dim3(512), 0, stream>>>(
        interb, I_, w2t, I_, b2, nullptr, logitsb, P_, I_);

    // candidate scan + exact f64 recheck -> routing (+ near-tie flagging)
    cand_scan<<<NTOK, blk, 0, stream>>>(logitsb, cidx, ccnt);
    recheck<<<NTOK, blk, 0, stream>>>(interf, w2tf, b2, cidx, ccnt, temp, tki, tkw,
                                      flagcnt, flaglist);

    // exact f64-from-x fallback for near-tied tokens
    fallback_gemv<<<1024, blk, 0, stream>>>(x, w1, flagcnt, flaglist, part);
    fallback_reduce<<<128, blk, 0, stream>>>(part, b1, w2tf, b2, cidx, ccnt,
                                             flagcnt, flaglist, temp, tki, tkw);

    // G4 (LDS MFMA, f32 A slot-stage convert): proj = x@wp+bp
    gemm_lds<0, 0><<<dim3(D_ / 128, NTOK / 128), blk, 0, stream>>>(
        x, H_, wpt, H_, bp, projb, nullptr, D_, H_);

    // LN + pool mix -> combined (bf16) + usage
    build_combined<<<NTOK, blk, 0, stream>>>(projb, comb, pool, gamma, beta, tki, tkw, usage);

    // G6 (256x128 pipelined bf16 MFMA, 256 blocks): out = combined@wm+bm (f32 store)
    gemm_pipe<0><<<dim3(D_ / 128, NTOK / 256), dim3(512), 0, stream>>>(
        comb, 2 * D_, wmt, 2 * D_, bm, out, nullptr, D_, 2 * D_);

    diversity_kernel<<<1, blk, 0, stream>>>(usage, out);
}

// Round 9
// 555.423 us; speedup vs baseline: 1.0651x; 1.0651x over previous
//
#include <hip/hip_runtime.h>
#include <hip/hip_bf16.h>
#include <float.h>
#include <limits.h>

#define NTOK 8192   // B*S
#define H_   2048
#define P_   4096
#define D_   1024
#define I_   1024

#define MAXC  16          // max recheck candidates per token
#define DELTA 0.09375f    // candidate margin (approx-logit worst err ~0.007)
#define TAU   4.0e-4f     // near-tie margin for exact fallback
#define FLAGCAP 512       // capped so part[] overlays the dead logitsb region

typedef unsigned short ushort_t;
typedef __attribute__((ext_vector_type(8))) short short8;   // 8 bf16 = 4 VGPRs
typedef __attribute__((ext_vector_type(4))) float floatx4;  // MFMA accumulator

static __device__ inline ushort_t f2bf(float f) {
    __hip_bfloat16 h = __float2bfloat16(f);   // RNE
    return *reinterpret_cast<ushort_t*>(&h);
}
static __device__ inline short f2bfs(float f) {
    __hip_bfloat16 h = __float2bfloat16(f);
    return *reinterpret_cast<short*>(&h);
}
static __device__ inline float bf2f(ushort_t s) { return __uint_as_float((unsigned)s << 16); }

static __device__ inline void ins2(float& v0, int& i0, float& v1, int& i1, float v, int i) {
    if (v > v0 || (v == v0 && i < i0)) { v1 = v0; i1 = i0; v0 = v; i0 = i; }
    else if (v > v1 || (v == v1 && i < i1)) { v1 = v; i1 = i; }
}

// direct global->LDS DMA, 16 B per lane (dest = wave-uniform base + lane*16)
static __device__ __forceinline__ void gload16(const void* g, void* l) {
    __builtin_amdgcn_global_load_lds(
        (const __attribute__((address_space(1))) unsigned int*)g,
        (__attribute__((address_space(3))) unsigned int*)l,
        16, 0, 0);
}

// ---------------------------------------------------------------------------
// fused weight prep (one launch): w2 -> w2t bf16 + w2tf f32 (transposed);
// wp -> wpt bf16; wm -> wmt bf16; w1 -> w1tHi/w1tLo bf16 split. All transposed.
// ---------------------------------------------------------------------------
__global__ __launch_bounds__(256) void prep_weights(
    const float* __restrict__ w2, float* __restrict__ w2tf, ushort_t* __restrict__ w2t,
    const float* __restrict__ wp, ushort_t* __restrict__ wpt,
    const float* __restrict__ wm, ushort_t* __restrict__ wmt,
    const float* __restrict__ w1, ushort_t* __restrict__ w1tHi, ushort_t* __restrict__ w1tLo)
{
    __shared__ float tile[32][33];
    const int tid = threadIdx.x;
    const int tx = tid & 31, ty = tid >> 5;   // 32 x 8
    int b = blockIdx.x;
    const float* in; int R, Cc, seg, bx, by;
    if (b < 4096)      { seg = 0; in = w2; R = I_; Cc = P_; bx = b & 127; by = b >> 7; }
    else if (b < 6144) { seg = 1; b -= 4096; in = wp; R = H_; Cc = D_; bx = b & 31; by = b >> 5; }
    else if (b < 8192) { seg = 2; b -= 6144; in = wm; R = H_; Cc = D_; bx = b & 31; by = b >> 5; }
    else               { seg = 3; b -= 8192; in = w1; R = H_; Cc = I_; bx = b & 31; by = b >> 5; }
    const int c0 = bx * 32, r0 = by * 32;
#pragma unroll
    for (int j = 0; j < 4; j++)
        tile[ty + j * 8][tx] = in[(size_t)(r0 + ty + j * 8) * Cc + c0 + tx];
    __syncthreads();
#pragma unroll
    for (int j = 0; j < 4; j++) {
        float v = tile[tx][ty + j * 8];
        const size_t o = (size_t)(c0 + ty + j * 8) * R + r0 + tx;
        if (seg == 0)      { w2t[o] = f2bf(v); w2tf[o] = v; }
        else if (seg == 1) { wpt[o] = f2bf(v); }
        else if (seg == 2) { wmt[o] = f2bf(v); }
        else { ushort_t h = f2bf(v); w1tHi[o] = h; w1tLo[o] = f2bf(v - bf2f(h)); }
    }
}

// ---------------------------------------------------------------------------
// pipeline staging helper: 16B slot p <-> (row=p>>2, chunk=(p^(p>>2))&3);
// inverse-swizzled SOURCE addr + linear LDS dest (both-sides rule).
// ---------------------------------------------------------------------------
static __device__ __forceinline__ void stage_slot(
    const ushort_t* __restrict__ base, int ld, int r0, int kt, int p,
    ushort_t* __restrict__ lds)
{
    const int row = p >> 2;
    const int chunk = (p ^ (p >> 2)) & 3;
    gload16(base + (size_t)(r0 + row) * ld + kt * 32 + chunk * 8, lds + p * 8);
}

// reg-stage converters: 8 f32 -> 1 hi short8 (+ optional lo short8), RNE
static __device__ __forceinline__ void cvt_write_hl(
    float4 v0, float4 v1, ushort_t* dh, ushort_t* dl)
{
    float fb[8] = {v0.x, v0.y, v0.z, v0.w, v1.x, v1.y, v1.z, v1.w};
    short8 h, l;
#pragma unroll
    for (int e = 0; e < 8; e++) {
        short hh = f2bfs(fb[e]);
        h[e] = hh;
        l[e] = f2bfs(fb[e] - bf2f((ushort_t)hh));
    }
    *(short8*)dh = h;
    *(short8*)dl = l;
}
static __device__ __forceinline__ void cvt_write_h(
    float4 v0, float4 v1, ushort_t* dh)
{
    float fb[8] = {v0.x, v0.y, v0.z, v0.w, v1.x, v1.y, v1.z, v1.w};
    short8 h;
#pragma unroll
    for (int e = 0; e < 8; e++) h[e] = f2bfs(fb[e]);
    *(short8*)dh = h;
}

// ---------------------------------------------------------------------------
// 256x128 deep-pipelined bf16 MFMA GEMM (T2/T3/T4/T5), plain bf16 operands.
// 512 thr = 8 waves (4M x 2N); per-wave C = 64x64 (4x4 frags of 16x16).
// LDS = 3 x (A 16KB + B 8KB) = 72 KB -> 2 blocks/CU. Steady gate vmcnt(3).
// ---------------------------------------------------------------------------
template<int EPI>
__global__ __launch_bounds__(512, 2) void gemm_pipe(
    const ushort_t* __restrict__ A, int lda,
    const ushort_t* __restrict__ Bt, int ldb,
    const float* __restrict__ bias,
    float* __restrict__ Cf, ushort_t* __restrict__ Cb, int ldc, int K)
{
    __shared__ ushort_t sA[3][256 * 32];   // 3 x 16 KB
    __shared__ ushort_t sB[3][128 * 32];   // 3 x  8 KB  -> 72 KB total

    const int tid  = threadIdx.x;
    const int wave = tid >> 6, lane = tid & 63;
    const int lr = lane & 15, lq = lane >> 4;
    const int wrow = wave >> 1, wcol = wave & 1;   // 4M x 2N

    const int nwg = gridDim.x * gridDim.y;
    int bid = blockIdx.y * gridDim.x + blockIdx.x;
    bid = (bid & 7) * (nwg >> 3) + (bid >> 3);
    const int bx = bid % gridDim.x, by = bid / gridDim.x;
    const int m0 = by * 256, n0 = bx * 128;
    const int NT = K >> 5;

    floatx4 acc[4][4] = {};

    stage_slot(A,  lda, m0, 0, tid,       &sA[0][0]);
    stage_slot(A,  lda, m0, 0, tid + 512, &sA[0][0]);
    stage_slot(Bt, ldb, n0, 0, tid,       &sB[0][0]);
    stage_slot(A,  lda, m0, 1, tid,       &sA[1][0]);
    stage_slot(A,  lda, m0, 1, tid + 512, &sA[1][0]);
    stage_slot(Bt, ldb, n0, 1, tid,       &sB[1][0]);

    for (int kt = 0; kt < NT; kt++) {
        const int cb = kt % 3;
        const int sbuf = (kt + 2) % 3;
        const bool st = (kt + 2) < NT;
        const ushort_t* __restrict__ sAc = &sA[cb][0];
        const ushort_t* __restrict__ sBc = &sB[cb][0];
        short8 bF[4];

#pragma unroll
        for (int p = 0; p < 2; p++) {
            if (p == 0) {
                if (kt + 1 < NT) asm volatile("s_waitcnt vmcnt(3)" ::: "memory");
                else             asm volatile("s_waitcnt vmcnt(0)" ::: "memory");
            }
            __builtin_amdgcn_s_barrier();
            short8 aF[2];
#pragma unroll
            for (int t = 0; t < 2; t++) {
                const int row = wrow * 64 + (2 * p + t) * 16 + lr;
                const int ph = row * 4 + (lq ^ (row & 3));
                aF[t] = *(const short8*)&sAc[ph * 8];
            }
            if (p == 0) {
#pragma unroll
                for (int f = 0; f < 4; f++) {
                    const int row = wcol * 64 + f * 16 + lr;
                    const int ph = row * 4 + (lq ^ (row & 3));
                    bF[f] = *(const short8*)&sBc[ph * 8];
                }
            }
            if (st) {
                if (p == 0) {
                    stage_slot(A,  lda, m0, kt + 2, tid, &sA[sbuf][0]);
                    stage_slot(Bt, ldb, n0, kt + 2, tid, &sB[sbuf][0]);
                } else {
                    stage_slot(A,  lda, m0, kt + 2, tid + 512, &sA[sbuf][0]);
                }
            }
            __builtin_amdgcn_s_setprio(1);
#pragma unroll
            for (int t = 0; t < 2; t++)
#pragma unroll
                for (int j = 0; j < 4; j++)
                    acc[2 * p + t][j] = __builtin_amdgcn_mfma_f32_16x16x32_bf16(
                        aF[t], bF[j], acc[2 * p + t][j], 0, 0, 0);
            __builtin_amdgcn_s_setprio(0);
        }
    }

#pragma unroll
    for (int j = 0; j < 4; j++) {
        const int col = n0 + wcol * 64 + j * 16 + lr;
        const float bv = bias[col];
#pragma unroll
        for (int i = 0; i < 4; i++) {
            const int rowb = m0 + wrow * 64 + i * 16 + lq * 4;
#pragma unroll
            for (int r = 0; r < 4; r++) {
                float v = acc[i][j][r] + bv;
                if (EPI == 1) Cb[(size_t)(rowb + r) * ldc + col] = f2bf(v);
                else          Cf[(size_t)(rowb + r) * ldc + col] = v;
            }
        }
    }
}

// ---------------------------------------------------------------------------
// 256x128 deep-pipelined SPLIT GEMM with in-kernel reg-staged A split:
//   C = relu( (hi(A)+lo(A)) @ (BH+BL)^T + bias ), dropping lo*lo.
// A is f32 (x); per tile kt, phase 1: ds_write hi/lo(A regs for kt+1, loaded
// one iteration earlier) + issue f32 loads for kt+2 (T14 async split).
// B hi/lo via gload_lds. Gate: vmcnt(6) = B(kt+1)x2 + A-regs(kt+1)x4 in
// flight; lgkmcnt(0) before phase-0 barrier makes ds_writes visible.
// Split math + MFMA order (HH,HL,LH) identical to prior rounds ->
// bit-identical inter; TAU margins unchanged. LDS 144 KB -> 1 block/CU.
// ---------------------------------------------------------------------------
__global__ __launch_bounds__(512, 2) void gemm_pipe_split_rs(
    const float* __restrict__ A, int lda,
    const ushort_t* __restrict__ BtH, const ushort_t* __restrict__ BtL, int ldb,
    const float* __restrict__ bias,
    float* __restrict__ Cf, ushort_t* __restrict__ Cb, int ldc, int K)
{
    __shared__ ushort_t sAh[3][256 * 32];   // 48 KB
    __shared__ ushort_t sAl[3][256 * 32];   // 48 KB
    __shared__ ushort_t sBh[3][128 * 32];   // 24 KB
    __shared__ ushort_t sBl[3][128 * 32];   // 24 KB -> 144 KB

    const int tid  = threadIdx.x;
    const int wave = tid >> 6, lane = tid & 63;
    const int lr = lane & 15, lq = lane >> 4;
    const int wrow = wave >> 1, wcol = wave & 1;

    const int nwg = gridDim.x * gridDim.y;
    int bid = blockIdx.y * gridDim.x + blockIdx.x;
    bid = (bid & 7) * (nwg >> 3) + (bid >> 3);
    const int bx = bid % gridDim.x, by = bid / gridDim.x;
    const int m0 = by * 256, n0 = bx * 128;
    const int NT = K >> 5;

    // A slot addresses for this thread: slots p1=tid, p2=tid+512
    const int p1 = tid, p2 = tid + 512;
    const float* a1p = A + (size_t)(m0 + (p1 >> 2)) * lda + ((p1 ^ (p1 >> 2)) & 3) * 8;
    const float* a2p = A + (size_t)(m0 + (p2 >> 2)) * lda + ((p2 ^ (p2 >> 2)) & 3) * 8;

    floatx4 acc[4][4] = {};
    float4 xa0, xa1, xb0, xb1;   // persistent f32 A regs (tile kt+1)

    // prologue: B tiles 0,1 (gload); A tile 0 load+convert+write; A tile 1 regs
    stage_slot(BtH, ldb, n0, 0, tid, &sBh[0][0]);
    stage_slot(BtL, ldb, n0, 0, tid, &sBl[0][0]);
    stage_slot(BtH, ldb, n0, 1, tid, &sBh[1][0]);
    stage_slot(BtL, ldb, n0, 1, tid, &sBl[1][0]);
    {
        float4 t0 = *(const float4*)(a1p);
        float4 t1 = *(const float4*)(a1p + 4);
        float4 t2 = *(const float4*)(a2p);
        float4 t3 = *(const float4*)(a2p + 4);
        cvt_write_hl(t0, t1, &sAh[0][p1 * 8], &sAl[0][p1 * 8]);
        cvt_write_hl(t2, t3, &sAh[0][p2 * 8], &sAl[0][p2 * 8]);
    }
    xa0 = *(const float4*)(a1p + 32);
    xa1 = *(const float4*)(a1p + 36);
    xb0 = *(const float4*)(a2p + 32);
    xb1 = *(const float4*)(a2p + 36);

    for (int kt = 0; kt < NT; kt++) {
        const int cb = kt % 3, sbuf = (kt + 2) % 3, wbuf = (kt + 1) % 3;
        const bool st1 = (kt + 1) < NT, st2 = (kt + 2) < NT;
        const ushort_t* __restrict__ sAhc = &sAh[cb][0];
        const ushort_t* __restrict__ sAlc = &sAl[cb][0];
        const ushort_t* __restrict__ sBhc = &sBh[cb][0];
        const ushort_t* __restrict__ sBlc = &sBl[cb][0];
        short8 bH[4], bL[4];

#pragma unroll
        for (int p = 0; p < 2; p++) {
            if (p == 0) {
                if (st1) asm volatile("s_waitcnt vmcnt(6)" ::: "memory");
                else     asm volatile("s_waitcnt vmcnt(0)" ::: "memory");
                asm volatile("s_waitcnt lgkmcnt(0)" ::: "memory");
            }
            __builtin_amdgcn_s_barrier();
            short8 aH[2], aL[2];
#pragma unroll
            for (int t = 0; t < 2; t++) {
                const int row = wrow * 64 + (2 * p + t) * 16 + lr;
                const int ph = (row * 4 + (lq ^ (row & 3))) * 8;
                aH[t] = *(const short8*)&sAhc[ph];
                aL[t] = *(const short8*)&sAlc[ph];
            }
            if (p == 0) {
#pragma unroll
                for (int f = 0; f < 4; f++) {
                    const int row = wcol * 64 + f * 16 + lr;
                    const int ph = (row * 4 + (lq ^ (row & 3))) * 8;
                    bH[f] = *(const short8*)&sBhc[ph];
                    bL[f] = *(const short8*)&sBlc[ph];
                }
                if (st2) {
                    stage_slot(BtH, ldb, n0, kt + 2, tid, &sBh[sbuf][0]);
                    stage_slot(BtL, ldb, n0, kt + 2, tid, &sBl[sbuf][0]);
                }
            } else {
                if (st1) {
                    // ds_write A(kt+1) hi/lo from regs (loaded during kt-1)
                    cvt_write_hl(xa0, xa1, &sAh[wbuf][p1 * 8], &sAl[wbuf][p1 * 8]);
                    cvt_write_hl(xb0, xb1, &sAh[wbuf][p2 * 8], &sAl[wbuf][p2 * 8]);
                }
                if (st2) {
                    // issue f32 loads for A(kt+2) into persistent regs
                    xa0 = *(const float4*)(a1p + (kt + 2) * 32);
                    xa1 = *(const float4*)(a1p + (kt + 2) * 32 + 4);
                    xb0 = *(const float4*)(a2p + (kt + 2) * 32);
                    xb1 = *(const float4*)(a2p + (kt + 2) * 32 + 4);
                }
            }
            __builtin_amdgcn_s_setprio(1);
#pragma unroll
            for (int t = 0; t < 2; t++)
#pragma unroll
                for (int j = 0; j < 4; j++) {
                    acc[2 * p + t][j] = __builtin_amdgcn_mfma_f32_16x16x32_bf16(
                        aH[t], bH[j], acc[2 * p + t][j], 0, 0, 0);
                    acc[2 * p + t][j] = __builtin_amdgcn_mfma_f32_16x16x32_bf16(
                        aH[t], bL[j], acc[2 * p + t][j], 0, 0, 0);
                    acc[2 * p + t][j] = __builtin_amdgcn_mfma_f32_16x16x32_bf16(
                        aL[t], bH[j], acc[2 * p + t][j], 0, 0, 0);
                }
            __builtin_amdgcn_s_setprio(0);
        }
    }

#pragma unroll
    for (int j = 0; j < 4; j++) {
        const int col = n0 + wcol * 64 + j * 16 + lr;
        const float bv = bias[col];
#pragma unroll
        for (int i = 0; i < 4; i++) {
            const int rowb = m0 + wrow * 64 + i * 16 + lq * 4;
#pragma unroll
            for (int r = 0; r < 4; r++) {
                float v = fmaxf(acc[i][j][r] + bv, 0.f);
                Cf[(size_t)(rowb + r) * ldc + col] = v;
                Cb[(size_t)(rowb + r) * ldc + col] = f2bf(v);
            }
        }
    }
}

// ---------------------------------------------------------------------------
// 256x128 deep-pipelined GEMM, A = f32 reg-staged + RNE convert to bf16
// (identical to old in-flight f2bfs -> bit-identical proj). B bf16 gload.
// Gate vmcnt(5) = B(kt+1)x1 + A-regs(kt+1)x4. LDS 72 KB -> 2 blocks/CU.
// f32 store + bias (G4).
// ---------------------------------------------------------------------------
__global__ __launch_bounds__(512, 2) void gemm_pipe_f32a(
    const float* __restrict__ A, int lda,
    const ushort_t* __restrict__ Bt, int ldb,
    const float* __restrict__ bias,
    float* __restrict__ Cf, int ldc, int K)
{
    __shared__ ushort_t sA[3][256 * 32];   // 48 KB
    __shared__ ushort_t sB[3][128 * 32];   // 24 KB -> 72 KB

    const int tid  = threadIdx.x;
    const int wave = tid >> 6, lane = tid & 63;
    const int lr = lane & 15, lq = lane >> 4;
    const int wrow = wave >> 1, wcol = wave & 1;

    const int nwg = gridDim.x * gridDim.y;
    int bid = blockIdx.y * gridDim.x + blockIdx.x;
    bid = (bid & 7) * (nwg >> 3) + (bid >> 3);
    const int bx = bid % gridDim.x, by = bid / gridDim.x;
    const int m0 = by * 256, n0 = bx * 128;
    const int NT = K >> 5;

    const int p1 = tid, p2 = tid + 512;
    const float* a1p = A + (size_t)(m0 + (p1 >> 2)) * lda + ((p1 ^ (p1 >> 2)) & 3) * 8;
    const float* a2p = A + (size_t)(m0 + (p2 >> 2)) * lda + ((p2 ^ (p2 >> 2)) & 3) * 8;

    floatx4 acc[4][4] = {};
    float4 xa0, xa1, xb0, xb1;

    stage_slot(Bt, ldb, n0, 0, tid, &sB[0][0]);
    stage_slot(Bt, ldb, n0, 1, tid, &sB[1][0]);
    {
        float4 t0 = *(const float4*)(a1p);
        float4 t1 = *(const float4*)(a1p + 4);
        float4 t2 = *(const float4*)(a2p);
        float4 t3 = *(const float4*)(a2p + 4);
        cvt_write_h(t0, t1, &sA[0][p1 * 8]);
        cvt_write_h(t2, t3, &sA[0][p2 * 8]);
    }
    xa0 = *(const float4*)(a1p + 32);
    xa1 = *(const float4*)(a1p + 36);
    xb0 = *(const float4*)(a2p + 32);
    xb1 = *(const float4*)(a2p + 36);

    for (int kt = 0; kt < NT; kt++) {
        const int cb = kt % 3, sbuf = (kt + 2) % 3, wbuf = (kt + 1) % 3;
        const bool st1 = (kt + 1) < NT, st2 = (kt + 2) < NT;
        const ushort_t* __restrict__ sAc = &sA[cb][0];
        const ushort_t* __restrict__ sBc = &sB[cb][0];
        short8 bF[4];

#pragma unroll
        for (int p = 0; p < 2; p++) {
            if (p == 0) {
                if (st1) asm volatile("s_waitcnt vmcnt(5)" ::: "memory");
                else     asm volatile("s_waitcnt vmcnt(0)" ::: "memory");
                asm volatile("s_waitcnt lgkmcnt(0)" ::: "memory");
            }
            __builtin_amdgcn_s_barrier();
            short8 aF[2];
#pragma unroll
            for (int t = 0; t < 2; t++) {
                const int row = wrow * 64 + (2 * p + t) * 16 + lr;
                const int ph = row * 4 + (lq ^ (row & 3));
                aF[t] = *(const short8*)&sAc[ph * 8];
            }
            if (p == 0) {
#pragma unroll
                for (int f = 0; f < 4; f++) {
                    const int row = wcol * 64 + f * 16 + lr;
                    const int ph = row * 4 + (lq ^ (row & 3));
                    bF[f] = *(const short8*)&sBc[ph * 8];
                }
                if (st2) stage_slot(Bt, ldb, n0, kt + 2, tid, &sB[sbuf][0]);
            } else {
                if (st1) {
                    cvt_write_h(xa0, xa1, &sA[wbuf][p1 * 8]);
                    cvt_write_h(xb0, xb1, &sA[wbuf][p2 * 8]);
                }
                if (st2) {
                    xa0 = *(const float4*)(a1p + (kt + 2) * 32);
                    xa1 = *(const float4*)(a1p + (kt + 2) * 32 + 4);
                    xb0 = *(const float4*)(a2p + (kt + 2) * 32);
                    xb1 = *(const float4*)(a2p + (kt + 2) * 32 + 4);
                }
            }
            __builtin_amdgcn_s_setprio(1);
#pragma unroll
            for (int t = 0; t < 2; t++)
#pragma unroll
                for (int j = 0; j < 4; j++)
                    acc[2 * p + t][j] = __builtin_amdgcn_mfma_f32_16x16x32_bf16(
                        aF[t], bF[j], acc[2 * p + t][j], 0, 0, 0);
            __builtin_amdgcn_s_setprio(0);
        }
    }

#pragma unroll
    for (int j = 0; j < 4; j++) {
        const int col = n0 + wcol * 64 + j * 16 + lr;
        const float bv = bias[col];
#pragma unroll
        for (int i = 0; i < 4; i++) {
            const int rowb = m0 + wrow * 64 + i * 16 + lq * 4;
#pragma unroll
            for (int r = 0; r < 4; r++)
                Cf[(size_t)(rowb + r) * ldc + col] = acc[i][j][r] + bv;
        }
    }
}

// ---------------------------------------------------------------------------
// per-token: approx top-2 over bf16 logits; emit all indices within DELTA of
// the 2nd max (always includes the approx top-2 themselves), cap MAXC
// ---------------------------------------------------------------------------
__global__ __launch_bounds__(256) void cand_scan(
    const ushort_t* __restrict__ logitsb,
    int* __restrict__ cidx, int* __restrict__ ccnt)
{
    __shared__ float sv0[4], sv1[4];
    __shared__ int   scnt;
    const int tok = blockIdx.x;
    const int tid = threadIdx.x;
    const ushort_t* row = logitsb + (size_t)tok * P_;

    float my[16];
    {
        const uint4* rp = (const uint4*)(row + tid * 16);
        uint4 u0 = rp[0], u1 = rp[1];
        unsigned w[8] = {u0.x, u0.y, u0.z, u0.w, u1.x, u1.y, u1.z, u1.w};
#pragma unroll
        for (int j = 0; j < 8; j++) {
            my[2 * j]     = __uint_as_float(w[j] << 16);
            my[2 * j + 1] = __uint_as_float(w[j] & 0xFFFF0000u);
        }
    }
    float v0 = -FLT_MAX, v1 = -FLT_MAX;
#pragma unroll
    for (int j = 0; j < 16; j++) {
        float v = my[j];
        if (v > v0) { v1 = v0; v0 = v; } else if (v > v1) v1 = v;
    }
#pragma unroll
    for (int off = 1; off < 64; off <<= 1) {
        float u0 = __shfl_xor(v0, off), u1 = __shfl_xor(v1, off);
        float n0 = fmaxf(v0, u0);
        float n1 = fmaxf(fminf(v0, u0), fmaxf(v1, u1));
        v0 = n0; v1 = n1;
    }
    const int wv = tid >> 6;
    if ((tid & 63) == 0) { sv0[wv] = v0; sv1[wv] = v1; }
    if (tid == 0) scnt = 0;
    __syncthreads();
    float g0 = -FLT_MAX, g1 = -FLT_MAX;
#pragma unroll
    for (int w = 0; w < 4; w++) {
        float u0 = sv0[w], u1 = sv1[w];
        float n0 = fmaxf(g0, u0);
        float n1 = fmaxf(fminf(g0, u0), fmaxf(g1, u1));
        g0 = n0; g1 = n1;
    }
    const float thresh = g1 - DELTA;
#pragma unroll
    for (int j = 0; j < 16; j++) {
        if (my[j] >= thresh) {
            int pos = atomicAdd(&scnt, 1);
            if (pos < MAXC) cidx[tok * MAXC + pos] = tid * 16 + j;
        }
    }
    __syncthreads();
    if (tid == 0) ccnt[tok] = min(scnt, MAXC);
}

// ---------------------------------------------------------------------------
// exact f64 recheck of candidate logits -> exact top-2 + softmax weights.
// If the (rank2 - rank3) gap is < TAU, flag the token for the exact fallback.
// ---------------------------------------------------------------------------
__global__ __launch_bounds__(256) void recheck(
    const float* __restrict__ interf, const float* __restrict__ w2tf,
    const float* __restrict__ b2, const int* __restrict__ cidx,
    const int* __restrict__ ccnt, const float* __restrict__ temp_p,
    int2* __restrict__ tki, float2* __restrict__ tkw,
    int* __restrict__ flagcnt, int* __restrict__ flaglist)
{
    __shared__ double ex[MAXC];
    __shared__ int    sidx[MAXC];
    const int tok  = blockIdx.x;
    const int tid  = threadIdx.x;
    const int wave = tid >> 6, lane = tid & 63;
    int cnt = min(max(ccnt[tok], 0), MAXC);

    const float* ir = interf + (size_t)tok * I_;
    for (int c = wave; c < cnt; c += 4) {
        int p = min(max(cidx[tok * MAXC + c], 0), P_ - 1);
        const float* wr = w2tf + (size_t)p * I_;
        double s = 0.0;
        for (int k = lane; k < I_; k += 64)
            s += (double)ir[k] * (double)wr[k];
#pragma unroll
        for (int off = 32; off; off >>= 1) s += __shfl_down(s, off);
        if (lane == 0) { ex[c] = s + (double)b2[p]; sidx[c] = p; }
    }
    __syncthreads();
    if (tid == 0) {
        float v0 = -FLT_MAX, v1 = -FLT_MAX; int i0 = INT_MAX, i1 = INT_MAX;
        for (int c = 0; c < cnt; c++) ins2(v0, i0, v1, i1, (float)ex[c], sidx[c]);
        if (i0 == INT_MAX) { i0 = 0; v0 = 0.f; }
        if (i1 == INT_MAX) { i1 = i0; v1 = v0; }
        if (cnt >= 3) {
            float v2 = -FLT_MAX;
            for (int c = 0; c < cnt; c++) {
                if (sidx[c] == i0 || sidx[c] == i1) continue;
                float v = (float)ex[c];
                if (v > v2) v2 = v;
            }
            if (v1 - v2 < TAU) {
                int pos = atomicAdd(flagcnt, 1);
                if (pos < FLAGCAP) flaglist[pos] = tok;
            }
        }
        float tc = fminf(fmaxf(temp_p[0], 0.1f), 5.0f);
        float s0 = fminf(fmaxf(v0 / tc, -10.f), 10.f);
        float s1 = fminf(fmaxf(v1 / tc, -10.f), 10.f);
        float m  = fmaxf(s0, s1);
        float e0 = expf(s0 - m), e1 = expf(s1 - m);
        float inv = 1.0f / (e0 + e1);
        tki[tok] = make_int2(i0, i1);
        tkw[tok] = make_float2(e0 * inv, e1 * inv);
    }
}

// ---------------------------------------------------------------------------
// fallback phase A: 16 blocks per flagged token; block (fi, slice) computes
// f64 partial inter over h in [slice*128, slice*128+128) for all 1024 i.
// ---------------------------------------------------------------------------
__global__ __launch_bounds__(256) void fallback_gemv(
    const float* __restrict__ x, const float* __restrict__ w1,
    const int* __restrict__ flagcnt, const int* __restrict__ flaglist,
    double* __restrict__ part)
{
    __shared__ float sx[128];
    const int tid = threadIdx.x;
    const int nf = min(flagcnt[0], FLAGCAP);
    const int nitems = nf * 16;

    for (int idx = blockIdx.x; idx < nitems; idx += gridDim.x) {
        const int fi = idx >> 4, slice = idx & 15;
        const int tok = flaglist[fi];
        const int h0 = slice * 128;
        __syncthreads();   // protect sx reuse across idx iterations
        if (tid < 128) sx[tid] = x[(size_t)tok * H_ + h0 + tid];
        __syncthreads();

        const int col = tid * 4;
        double a0 = 0.0, a1 = 0.0, a2 = 0.0, a3 = 0.0;
        for (int h = 0; h < 128; h += 8) {
            float4 wv[8];
#pragma unroll
            for (int u = 0; u < 8; u++)
                wv[u] = *(const float4*)(w1 + (size_t)(h0 + h + u) * I_ + col);
#pragma unroll
            for (int u = 0; u < 8; u++) {
                const double xv = (double)sx[h + u];
                a0 += xv * (double)wv[u].x;
                a1 += xv * (double)wv[u].y;
                a2 += xv * (double)wv[u].z;
                a3 += xv * (double)wv[u].w;
            }
        }
        double* pp = part + ((size_t)fi * 16 + slice) * I_ + col;
        pp[0] = a0; pp[1] = a1; pp[2] = a2; pp[3] = a3;
    }
}

// ---------------------------------------------------------------------------
// fallback phase B: per flagged token, reduce 16 partials + bias + relu ->
// exact candidate logits (f64) -> top-2 + softmax weights.
// ---------------------------------------------------------------------------
__global__ __launch_bounds__(256) void fallback_reduce(
    const double* __restrict__ part, const float* __restrict__ b1,
    const float* __restrict__ w2tf, const float* __restrict__ b2,
    const int* __restrict__ cidx, const int* __restrict__ ccnt,
    const int* __restrict__ flagcnt, const int* __restrict__ flaglist,
    const float* __restrict__ temp_p,
    int2* __restrict__ tki, float2* __restrict__ tkw)
{
    __shared__ double sInter[I_];   // 8 KB
    __shared__ double ex[MAXC];
    __shared__ int    sidx[MAXC];
    const int tid  = threadIdx.x;
    const int wave = tid >> 6, lane = tid & 63;
    const int nf = min(flagcnt[0], FLAGCAP);

    for (int fi = blockIdx.x; fi < nf; fi += gridDim.x) {
        const int tok = flaglist[fi];
        __syncthreads();   // protect LDS reuse across fi iterations
#pragma unroll
        for (int q = 0; q < 4; q++) {
            const int i = q * 256 + tid;
            double v = (double)b1[i];
            const double* pp = part + (size_t)fi * 16 * I_ + i;
#pragma unroll
            for (int s = 0; s < 16; s++) v += pp[(size_t)s * I_];
            sInter[i] = v > 0.0 ? v : 0.0;
        }
        __syncthreads();

        const int cnt = min(max(ccnt[tok], 0), MAXC);
        for (int c = wave; c < cnt; c += 4) {
            int p = min(max(cidx[tok * MAXC + c], 0), P_ - 1);
            const float* wr = w2tf + (size_t)p * I_;
            double s = 0.0;
            for (int k = lane; k < I_; k += 64)
                s += sInter[k] * (double)wr[k];
#pragma unroll
            for (int off = 32; off; off >>= 1) s += __shfl_down(s, off);
            if (lane == 0) { ex[c] = s + (double)b2[p]; sidx[c] = p; }
        }
        __syncthreads();
        if (tid == 0) {
            float v0 = -FLT_MAX, v1 = -FLT_MAX; int i0 = INT_MAX, i1 = INT_MAX;
            for (int c = 0; c < cnt; c++) ins2(v0, i0, v1, i1, (float)ex[c], sidx[c]);
            if (i0 == INT_MAX) { i0 = 0; v0 = 0.f; }
            if (i1 == INT_MAX) { i1 = i0; v1 = v0; }
            float tc = fminf(fmaxf(temp_p[0], 0.1f), 5.0f);
            float s0 = fminf(fmaxf(v0 / tc, -10.f), 10.f);
            float s1 = fminf(fmaxf(v1 / tc, -10.f), 10.f);
            float m  = fmaxf(s0, s1);
            float e0 = expf(s0 - m), e1 = expf(s1 - m);
            float inv = 1.0f / (e0 + e1);
            tki[tok] = make_int2(i0, i1);
            tkw[tok] = make_float2(e0 * inv, e1 * inv);
        }
    }
}

// ---------------------------------------------------------------------------
static __device__ inline float blockReduceSum256(float v, float* red) {
#pragma unroll
    for (int off = 32; off; off >>= 1) v += __shfl_down(v, off);
    const int wv = threadIdx.x >> 6;
    if ((threadIdx.x & 63) == 0) red[wv] = v;
    __syncthreads();
    float tot = red[0] + red[1] + red[2] + red[3];
    __syncthreads();
    return tot;
}

// ---------------------------------------------------------------------------
// combined(bf16)[tok] = [ LN(proj)*gamma+beta , w0*pool[i0]+w1*pool[i1] ] + usage
// ---------------------------------------------------------------------------
__global__ __launch_bounds__(256) void build_combined(
    const float* __restrict__ proj, ushort_t* __restrict__ comb,
    const float* __restrict__ pool,
    const float* __restrict__ gamma, const float* __restrict__ beta,
    const int2* __restrict__ tki, const float2* __restrict__ tkw,
    float* __restrict__ usage)
{
    __shared__ float red[4];
    const int tok = blockIdx.x;
    const int tid = threadIdx.x;
    const int c = tid * 4;

    float4 v = *(const float4*)&proj[(size_t)tok * D_ + c];
    float s = v.x + v.y + v.z + v.w;
    float tot = blockReduceSum256(s, red);
    float mu = tot * (1.0f / D_);
    float d0 = v.x - mu, d1 = v.y - mu, d2 = v.z - mu, d3 = v.w - mu;
    float sq = d0 * d0 + d1 * d1 + d2 * d2 + d3 * d3;
    float var = blockReduceSum256(sq, red) * (1.0f / D_);
    float rs = 1.0f / sqrtf(var + 1e-5f);

    float4 g  = *(const float4*)&gamma[c];
    float4 be = *(const float4*)&beta[c];
    ushort4 o;
    o.x = f2bf(d0 * rs * g.x + be.x);
    o.y = f2bf(d1 * rs * g.y + be.y);
    o.z = f2bf(d2 * rs * g.z + be.z);
    o.w = f2bf(d3 * rs * g.w + be.w);
    *(ushort4*)&comb[(size_t)tok * (2 * D_) + c] = o;

    int2   ii = tki[tok];
    int ia = min(max(ii.x, 0), P_ - 1);
    int ib = min(max(ii.y, 0), P_ - 1);
    float2 ww = tkw[tok];
    float4 p0 = *(const float4*)&pool[(size_t)ia * D_ + c];
    float4 p1 = *(const float4*)&pool[(size_t)ib * D_ + c];
    ushort4 wm;
    wm.x = f2bf(ww.x * p0.x + ww.y * p1.x);
    wm.y = f2bf(ww.x * p0.y + ww.y * p1.y);
    wm.z = f2bf(ww.x * p0.z + ww.y * p1.z);
    wm.w = f2bf(ww.x * p0.w + ww.y * p1.w);
    *(ushort4*)&comb[(size_t)tok * (2 * D_) + D_ + c] = wm;

    if (tid == 0) {
        atomicAdd(&usage[ia], ww.x);
        atomicAdd(&usage[ib], ww.y);
    }
}

// ---------------------------------------------------------------------------
__global__ __launch_bounds__(256) void diversity_kernel(
    const float* __restrict__ usage, float* __restrict__ out)
{
    __shared__ float red[4];
    const int tid = threadIdx.x;
    float s = 0.f;
    for (int j = tid; j < P_; j += 256) s += usage[j];
    float tot = blockReduceSum256(s, red) + 1e-8f;
    float q = 0.f;
    const float uni = 1.0f / P_;
    for (int j = tid; j < P_; j += 256) {
        float f = usage[j] / tot - uni;
        q += f * f;
    }
    float ssq = blockReduceSum256(q, red);
    if (tid == 0) out[(size_t)NTOK * D_] = ssq * (1.0f / P_) * 0.01f;
}

// ---------------------------------------------------------------------------
extern "C" void kernel_launch(void* const* d_in, const int* in_sizes, int n_in,
                              void* d_out, int out_size, void* d_ws, size_t ws_size,
                              hipStream_t stream) {
    const float* x     = (const float*)d_in[0];
    const float* pool  = (const float*)d_in[1];
    const float* w1    = (const float*)d_in[3];
    const float* b1    = (const float*)d_in[4];
    const float* w2    = (const float*)d_in[5];
    const float* b2    = (const float*)d_in[6];
    const float* temp  = (const float*)d_in[7];
    const float* wp    = (const float*)d_in[8];
    const float* bp    = (const float*)d_in[9];
    const float* gamma = (const float*)d_in[10];
    const float* beta  = (const float*)d_in[11];
    const float* wm    = (const float*)d_in[12];
    const float* bm    = (const float*)d_in[13];
    float* out = (float*)d_out;

    // workspace map (float offsets), peak ~153 MB:
    //  [0,8M)     interf f32 [8192][1024]
    //  [8M,12M)   interb bf16 [8192][1024]
    //  [12M,28M)  phase 1: logitsb bf16 [8192][4096] (G2 -> cand_scan)
    //             phase 2: part f64 [512][16][1024] (fallback, 64 MB)
    //             phase 3: proj f32 @12M, combined bf16 @20M
    //  [28M,32M)  w2tf f32; [32M,34M) w2t; [34M,35M) wpt; [35M,36M) wmt
    //  [36M,37M)  w1tHi; [37M,38M) w1tLo; [38M,...) small buffers
    float* ws = (float*)d_ws;
    const size_t MF = (size_t)1024 * 1024;
    float*    interf  = ws;
    ushort_t* interb  = (ushort_t*)(ws + 8 * MF);
    ushort_t* logitsb = (ushort_t*)(ws + 12 * MF);
    double*   part    = (double*)(ws + 12 * MF);
    float*    projb   = ws + 12 * MF;
    ushort_t* comb    = (ushort_t*)(ws + 20 * MF);
    float*    w2tf    = ws + 28 * MF;
    ushort_t* w2t     = (ushort_t*)(ws + 32 * MF);
    ushort_t* wpt     = (ushort_t*)(ws + 34 * MF);
    ushort_t* wmt     = (ushort_t*)(ws + 35 * MF);
    ushort_t* w1tHi   = (ushort_t*)(ws + 36 * MF);
    ushort_t* w1tLo   = (ushort_t*)(ws + 37 * MF);
    int*      cidx    = (int*)(ws + 38 * MF);
    int*      ccnt    = cidx + NTOK * MAXC;
    int2*     tki     = (int2*)(ccnt + NTOK);
    float2*   tkw     = (float2*)(tki + NTOK);
    float*    usage   = (float*)(tkw + NTOK);
    int*      flagcnt = (int*)(usage + P_);
    int*      flaglist= flagcnt + 1;

    hipMemsetAsync(usage, 0, (P_ + 1) * sizeof(float), stream);  // usage + flagcnt

    dim3 blk(256);
    // fused weight prep
    prep_weights<<<10240, blk, 0, stream>>>(w2, w2tf, w2t, wp, wpt, wm, wmt,
                                            w1, w1tHi, w1tLo);

    // G1 (256x128 pipelined split MFMA, in-kernel A split): inter = relu(x@w1+b1)
    gemm_pipe_split_rs<<<dim3(I_ / 128, NTOK / 256), dim3(512), 0, stream>>>(
        x, H_, w1tHi, w1tLo, H_, b1, interf, interb, I_, H_);

    // G2 (256x128 pipelined bf16 MFMA, 1024 blocks): approx logits (bf16 store)
    gemm_pipe<1><<<dim3(P_ / 128, NTOK / 256), dim3(512), 0, stream>>>(
        interb, I_, w2t, I_, b2, nullptr, logitsb, P_, I_);

    // candidate scan + exact f64 recheck -> routing (+ near-tie flagging)
    cand_scan<<<NTOK, blk, 0, stream>>>(logitsb, cidx, ccnt);
    recheck<<<NTOK, blk, 0, stream>>>(interf, w2tf, b2, cidx, ccnt, temp, tki, tkw,
                                      flagcnt, flaglist);

    // exact f64-from-x fallback for near-tied tokens
    fallback_gemv<<<1024, blk, 0, stream>>>(x, w1, flagcnt, flaglist, part);
    fallback_reduce<<<128, blk, 0, stream>>>(part, b1, w2tf, b2, cidx, ccnt,
                                             flagcnt, flaglist, temp, tki, tkw);

    // G4 (256x128 pipelined, f32 A reg-staged convert): proj = x@wp+bp (f32 store)
    gemm_pipe_f32a<<<dim3(D_ / 128, NTOK / 256), dim3(512), 0, stream>>>(
        x, H_, wpt, H_, bp, projb, D_, H_);

    // LN + pool mix -> combined (bf16) + usage
    build_combined<<<NTOK, blk, 0, stream>>>(projb, comb, pool, gamma, beta, tki, tkw, usage);

    // G6 (256x128 pipelined bf16 MFMA, 256 blocks): out = combined@wm+bm (f32 store)
    gemm_pipe<0><<<dim3(D_ / 128, NTOK / 256), dim3(512), 0, stream>>>(
        comb, 2 * D_, wmt, 2 * D_, bm, out, nullptr, D_, 2 * D_);

    diversity_kernel<<<1, blk, 0, stream>>>(usage, out);
}